// Round 12
// baseline (561.422 us; speedup 1.0000x reference)
//
#include <hip/hip_runtime.h>
#include <math.h>

#define NND 10000
#define NE  160000
#define HD  128
#define NH  (NND*HD)   // 1,280,000

typedef _Float16 f16;
typedef _Float16 half8 __attribute__((ext_vector_type(8)));
typedef _Float16 half4 __attribute__((ext_vector_type(4)));
typedef float floatx4 __attribute__((ext_vector_type(4)));

__device__ __forceinline__ float silu_f(float v) {
    return v * (1.0f / (1.0f + __expf(-v)));
}

// ---------------------------------------------------------------------------
// K0: weights -> fp16, transposed to [N][K] for contiguous fragment loads.
// ---------------------------------------------------------------------------
__global__ __launch_bounds__(256) void w_prep(const float* __restrict__ W1,
                                              const float* __restrict__ W2,
                                              const float* __restrict__ W3,
                                              const float* __restrict__ Wt,
                                              f16* __restrict__ w1t,
                                              f16* __restrict__ w2t,
                                              f16* __restrict__ w3t,
                                              f16* __restrict__ wtT) {
    int id = blockIdx.x * 256 + threadIdx.x;
    if (id < 128*64) { int n = id >> 6, k = id & 63;  w1t[id] = (f16)W1[k*128 + n]; return; }
    id -= 128*64;
    if (id < 256*128) { int n = id >> 7, k = id & 127; w2t[id] = (f16)W2[k*256 + n]; return; }
    id -= 256*128;
    if (id < 384*256) { int n = id >> 8, k = id & 255; w3t[id] = (f16)W3[k*384 + n]; return; }
    id -= 384*256;
    if (id < 6*128*128) {
        int wi = id >> 14, rem = id & 16383;
        int n = rem >> 7, k = rem & 127;
        wtT[(size_t)wi*16384 + n*128 + k] = (f16)Wt[(size_t)wi*16384 + k*128 + n];
    }
}

// ---------------------------------------------------------------------------
// Counting sort of edges by src: histogram -> scan -> scatter
// ---------------------------------------------------------------------------
__global__ __launch_bounds__(256) void hist_kernel(const int* __restrict__ eidx,
                                                   int* __restrict__ hist) {
    int e = blockIdx.x * 256 + threadIdx.x;
    if (e < NE) atomicAdd(&hist[eidx[e]], 1);
}

__global__ __launch_bounds__(1024) void scan_kernel(const int* __restrict__ hist,
                                                    int* __restrict__ offs,
                                                    int* __restrict__ cursor) {
    __shared__ int sums[1024];
    int t = threadIdx.x;
    int base = t * 10;
    int loc[10]; int s = 0;
    #pragma unroll
    for (int i = 0; i < 10; i++) {
        int v = (base + i < NND) ? hist[base + i] : 0;
        loc[i] = s; s += v;
    }
    sums[t] = s;
    __syncthreads();
    for (int off = 1; off < 1024; off <<= 1) {
        int v = (t >= off) ? sums[t - off] : 0;
        __syncthreads();
        sums[t] += v;
        __syncthreads();
    }
    int basesum = (t > 0) ? sums[t - 1] : 0;
    #pragma unroll
    for (int i = 0; i < 10; i++)
        if (base + i < NND) { offs[base + i] = basesum + loc[i]; cursor[base + i] = basesum + loc[i]; }
}

__global__ __launch_bounds__(256) void scatter_kernel(const int* __restrict__ eidx,
                                                      int* __restrict__ cursor,
                                                      int* __restrict__ perm,
                                                      int* __restrict__ ssrc,
                                                      int* __restrict__ sdst) {
    int e = blockIdx.x * 256 + threadIdx.x;
    if (e >= NE) return;
    int s = eidx[e], d = eidx[NE + e];
    int pos = atomicAdd(&cursor[s], 1);
    perm[pos] = e; ssrc[pos] = s; sdst[pos] = d;
}

// ---------------------------------------------------------------------------
// K1: normalize X, decompose into 10 scalar fields [f][n][h] (f16)
// ---------------------------------------------------------------------------
__global__ __launch_bounds__(256) void node_prep(const float* __restrict__ X,
                                                 f16* __restrict__ comp) {
    int idx = blockIdx.x * 256 + threadIdx.x;
    if (idx >= NH) return;
    const float* xp = X + (size_t)idx * 9;
    float x[9];
    #pragma unroll
    for (int i = 0; i < 9; i++) x[i] = xp[i];
    float nsq = 0.f;
    #pragma unroll
    for (int i = 0; i < 9; i++) nsq = fmaf(x[i], x[i], nsq);
    float inv = 1.0f / (nsq + 1.0f);
    #pragma unroll
    for (int i = 0; i < 9; i++) x[i] *= inv;

    float I0  = (x[0] + x[4] + x[8]) * (1.0f / 3.0f);
    float a0  = 0.5f * (x[7] - x[5]);
    float a1  = 0.5f * (x[2] - x[6]);
    float a2  = 0.5f * (x[3] - x[1]);
    float s00 = x[0] - I0;
    float s11 = x[4] - I0;
    float s22 = x[8] - I0;
    float s01 = 0.5f * (x[1] + x[3]);
    float s02 = 0.5f * (x[2] + x[6]);
    float s12 = 0.5f * (x[5] + x[7]);

    comp[0*NH + idx] = (f16)I0;
    comp[1*NH + idx] = (f16)a0;  comp[2*NH + idx] = (f16)a1;  comp[3*NH + idx] = (f16)a2;
    comp[4*NH + idx] = (f16)s00; comp[5*NH + idx] = (f16)s11; comp[6*NH + idx] = (f16)s22;
    comp[7*NH + idx] = (f16)s01; comp[8*NH + idx] = (f16)s02; comp[9*NH + idx] = (f16)s12;
}

// ---------------------------------------------------------------------------
// K2: channel-mix GEMM via fp16 MFMA.
// writeNode: f16 channel-major [node][128][16] (planes 0..9 + pad).
// writePlane: f16 plane-major [plane*NND+node][128].
// ---------------------------------------------------------------------------
__global__ __launch_bounds__(256) void mix_mfma(const f16* __restrict__ A,
                                                const f16* __restrict__ WtT,
                                                f16* __restrict__ Cn,
                                                f16* __restrict__ Cp,
                                                int w0, int w1, int w2,
                                                int writeNode, int writePlane) {
    const int g = blockIdx.y;
    const int baseRow = (g == 0) ? 0   : (g == 1 ? NND   : 4*NND);
    const int Mg      = (g == 0) ? NND : (g == 1 ? 3*NND : 6*NND);
    const int row0 = blockIdx.x * 64;
    if (row0 >= Mg) return;
    const int wi = (g == 0) ? w0 : (g == 1 ? w1 : w2);
    const f16* B = WtT + (size_t)wi * 128 * 128;

    __shared__ f16 As[64 * 136];

    const int t = threadIdx.x;
    const int l = t & 63, wid = t >> 6, lr = l & 15, lh = l >> 4;

    #pragma unroll
    for (int i = 0; i < 4; i++) {
        int id = t + 256 * i;
        int r = id >> 4, ch = id & 15;
        int rr = row0 + r; if (rr >= Mg) rr = Mg - 1;
        *(half8*)&As[r*136 + ch*8] =
            *(const half8*)&A[((size_t)baseRow + rr) * HD + ch*8];
    }
    __syncthreads();

    floatx4 acc[8];
    #pragma unroll
    for (int n = 0; n < 8; n++) acc[n] = (floatx4)0.0f;

    #pragma unroll
    for (int k0 = 0; k0 < 128; k0 += 32) {
        half8 a = *(const half8*)&As[(wid*16 + lr)*136 + k0 + lh*8];
        #pragma unroll
        for (int n = 0; n < 8; n++) {
            half8 b = *(const half8*)&B[(size_t)(n*16 + lr)*128 + k0 + lh*8];
            acc[n] = __builtin_amdgcn_mfma_f32_16x16x32_f16(a, b, acc[n], 0, 0, 0);
        }
    }

    #pragma unroll
    for (int n = 0; n < 8; n++) {
        #pragma unroll
        for (int r = 0; r < 4; r++) {
            int gl = row0 + wid*16 + lh*4 + r;
            if (gl < Mg) {
                size_t grow = (size_t)baseRow + gl;
                int col = n*16 + lr;
                float val = acc[n][r];
                if (writePlane) Cp[grow * HD + col] = (f16)val;
                if (writeNode) {
                    int plane = (int)(grow / NND);
                    int node  = (int)(grow - (size_t)plane * NND);
                    Cn[(size_t)node*2048 + (size_t)col*16 + plane] = (f16)val;
                }
            }
        }
    }
}

// ---------------------------------------------------------------------------
// K3a: fused layers 1+2 (proven config: bounds(256,4), 33 KB pool).
// ---------------------------------------------------------------------------
__global__ __launch_bounds__(256, 4) void edge_gemm12(
    const float* __restrict__ edge_attr, const float* __restrict__ charges,
    const int* __restrict__ offs,
    const int* __restrict__ perm, const int* __restrict__ ssrc, const int* __restrict__ sdst,
    const f16* __restrict__ W1t, const float* __restrict__ b1,
    const f16* __restrict__ W2t, const float* __restrict__ b2,
    f16* __restrict__ x2b, int n0, int n1)
{
    __shared__ __align__(16) char pool[33280];
    f16* x0s  = (f16*)pool;                // 64*72*2  = 9216
    f16* x1s  = (f16*)(pool + 9216);       // 64*140*2 = 17920 (ends 27136)
    f16* x2st = (f16*)pool;                // 64*260*2 = 33280 (aliases, post-MFMA)
    __shared__ int srcS[64], dstS[64], permS[64];

    const int pbase = offs[n0];
    const int pend  = (n1 >= NND) ? NE : offs[n1];
    const int eb    = blockIdx.x * 64;
    if (pbase + eb >= pend) return;

    const int t = threadIdx.x;
    const int l = t & 63, wid = t >> 6, lr = l & 15, lh = l >> 4;

    if (t < 64) {
        int pe = pbase + eb + t;
        if (pe > NE - 1) pe = NE - 1;
        permS[t] = perm[pe];
        srcS[t]  = ssrc[pe];
        dstS[t]  = sdst[pe];
    }
    __syncthreads();

    // gather-stage: [attr(32) | charges[src](16) | charges[dst](16)]
    {
        int e = t >> 2, q = t & 3;
        #pragma unroll
        for (int jj = 0; jj < 2; jj++) {
            int j = q + jj*4;
            float4 va = *(const float4*)&edge_attr[(size_t)permS[e]*32 + j*4];
            half4 hv; hv[0]=(f16)va.x; hv[1]=(f16)va.y; hv[2]=(f16)va.z; hv[3]=(f16)va.w;
            *(half4*)&x0s[e*72 + j*4] = hv;
        }
        int node = (q < 2) ? srcS[e] : dstS[e];
        int qq   = (q < 2) ? q : (q - 2);
        int cb   = (q < 2) ? 32 : 48;
        #pragma unroll
        for (int jj = 0; jj < 2; jj++) {
            int j = qq + jj*2;
            float4 vc = *(const float4*)&charges[(size_t)node*16 + j*4];
            half4 hv; hv[0]=(f16)vc.x; hv[1]=(f16)vc.y; hv[2]=(f16)vc.z; hv[3]=(f16)vc.w;
            *(half4*)&x0s[e*72 + cb + j*4] = hv;
        }
    }
    __syncthreads();

    // ---- layer 1: [64 e][64 k] @ W1t[128][64] -> x1s (LDS) ----
    {
        floatx4 acc[2][4];
        #pragma unroll
        for (int n = 0; n < 2; n++)
            #pragma unroll
            for (int m = 0; m < 4; m++) acc[n][m] = (floatx4)0.0f;

        #pragma unroll
        for (int k0 = 0; k0 < 64; k0 += 32) {
            half8 a[4];
            #pragma unroll
            for (int m = 0; m < 4; m++)
                a[m] = *(const half8*)&x0s[(m*16 + lr)*72 + k0 + lh*8];
            #pragma unroll
            for (int n = 0; n < 2; n++) {
                half8 b = *(const half8*)&W1t[(size_t)(wid*32 + n*16 + lr)*64 + k0 + lh*8];
                #pragma unroll
                for (int m = 0; m < 4; m++)
                    acc[n][m] = __builtin_amdgcn_mfma_f32_16x16x32_f16(a[m], b, acc[n][m], 0, 0, 0);
            }
        }
        #pragma unroll
        for (int n = 0; n < 2; n++) {
            int col = wid*32 + n*16 + lr;
            float bb = b1[col];
            #pragma unroll
            for (int m = 0; m < 4; m++)
                #pragma unroll
                for (int r = 0; r < 4; r++)
                    x1s[(m*16 + lh*4 + r)*140 + col] = (f16)silu_f(acc[n][m][r] + bb);
        }
    }
    __syncthreads();

    // ---- layer 2: x1s[64][128] @ W2t[256][128] -> x2st (LDS) -> global ----
    {
        floatx4 acc[4][4];
        #pragma unroll
        for (int n = 0; n < 4; n++)
            #pragma unroll
            for (int m = 0; m < 4; m++) acc[n][m] = (floatx4)0.0f;

        #pragma unroll
        for (int k0 = 0; k0 < 128; k0 += 32) {
            half8 a[4];
            #pragma unroll
            for (int m = 0; m < 4; m++)
                a[m] = *(const half8*)&x1s[(m*16 + lr)*140 + k0 + lh*8];
            #pragma unroll
            for (int n = 0; n < 4; n++) {
                half8 b = *(const half8*)&W2t[(size_t)(wid*64 + n*16 + lr)*128 + k0 + lh*8];
                #pragma unroll
                for (int m = 0; m < 4; m++)
                    acc[n][m] = __builtin_amdgcn_mfma_f32_16x16x32_f16(a[m], b, acc[n][m], 0, 0, 0);
            }
        }
        __syncthreads();            // all x0s/x1s reads done before aliasing x2st
        #pragma unroll
        for (int n = 0; n < 4; n++) {
            int col = wid*64 + n*16 + lr;
            float bb = b2[col];
            #pragma unroll
            for (int m = 0; m < 4; m++)
                #pragma unroll
                for (int r = 0; r < 4; r++)
                    x2st[(m*16 + lh*4 + r)*260 + col] = (f16)silu_f(acc[n][m][r] + bb);
        }
    }
    __syncthreads();

    #pragma unroll
    for (int i = 0; i < 8; i++) {
        int c = t + 256 * i;
        int e = c >> 5, j = c & 31;
        *(half8*)&x2b[(size_t)(eb + e)*256 + j*8] = *(const half8*)&x2st[e*260 + j*8];
    }
}

// ---------------------------------------------------------------------------
// K3a': layer 3. x2 [VC][256] -> vbuf [slot][128][4] f16 ((I,A,S,pad) per ch),
// cutoff-scaled. Full N=384, acc[6][4]; two-phase 32-row twisted staging.
// ---------------------------------------------------------------------------
__global__ __launch_bounds__(256) void edge_gemm3(
    const float* __restrict__ edge_weight,
    const int* __restrict__ offs, const int* __restrict__ perm,
    const f16* __restrict__ x2b,
    const f16* __restrict__ W3t, const float* __restrict__ b3,
    f16* __restrict__ vbuf, int n0, int n1)
{
    __shared__ __align__(16) char pool[33280];
    f16* As    = (f16*)pool;               // 64*136*2 = 17408
    f16* stage = (f16*)pool;               // 32*520*2 = 33280 (aliases, post-MFMA)
    __shared__ float Cs[64];

    const int pbase = offs[n0];
    const int pend  = (n1 >= NND) ? NE : offs[n1];
    const int eb    = blockIdx.x * 64;
    if (pbase + eb >= pend) return;

    const int t = threadIdx.x;
    const int l = t & 63, wid = t >> 6, lr = l & 15, lh = l >> 4;

    if (t < 64) {
        int pe = pbase + eb + t;
        if (pe > NE - 1) pe = NE - 1;
        float w = edge_weight[perm[pe]];
        float c = 0.5f * (cosf(w * (float)(M_PI / 4.5)) + 1.0f);
        Cs[t] = (w < 4.5f) ? c : 0.0f;
    }

    floatx4 acc[6][4];
    #pragma unroll
    for (int n = 0; n < 6; n++)
        #pragma unroll
        for (int m = 0; m < 4; m++) acc[n][m] = (floatx4)0.0f;

    #pragma unroll
    for (int kb = 0; kb < 2; kb++) {
        __syncthreads();
        #pragma unroll
        for (int i = 0; i < 4; i++) {
            int id = t + 256 * i;
            int r = id >> 4, c = id & 15;
            *(half8*)&As[r*136 + c*8] =
                *(const half8*)&x2b[(size_t)(eb + r)*256 + kb*128 + c*8];
        }
        __syncthreads();

        #pragma unroll
        for (int k0 = 0; k0 < 128; k0 += 32) {
            half8 a[4];
            #pragma unroll
            for (int m = 0; m < 4; m++)
                a[m] = *(const half8*)&As[(m*16 + lr)*136 + k0 + lh*8];
            #pragma unroll
            for (int n = 0; n < 6; n++) {
                half8 b = *(const half8*)&W3t[(size_t)(wid*96 + n*16 + lr)*256 + kb*128 + k0 + lh*8];
                #pragma unroll
                for (int m = 0; m < 4; m++)
                    acc[n][m] = __builtin_amdgcn_mfma_f32_16x16x32_f16(a[m], b, acc[n][m], 0, 0, 0);
            }
        }
    }
    __syncthreads();                 // As reads done before stage overwrite

    #pragma unroll
    for (int ph = 0; ph < 2; ph++) {
        #pragma unroll
        for (int n = 0; n < 6; n++) {
            int col = wid*96 + n*16 + lr;
            int gg = col >> 7, hc = col & 127;
            float bb = b3[col];
            #pragma unroll
            for (int mm = 0; mm < 2; mm++) {
                int m = ph*2 + mm;
                #pragma unroll
                for (int r = 0; r < 4; r++) {
                    int e  = mm*16 + lh*4 + r;          // row within phase
                    int ge = m*16 + lh*4 + r;           // global row (for Cs)
                    stage[e*520 + hc*4 + gg] = (f16)(silu_f(acc[n][m][r] + bb) * Cs[ge]);
                }
            }
        }
        __syncthreads();
        #pragma unroll
        for (int i = 0; i < 8; i++) {
            int c = t + 256 * i;              // 0..2047
            int e = c >> 6, j = c & 63;       // 32 rows x 64 half8s
            *(half8*)&vbuf[(size_t)(eb + ph*32 + e)*512 + j*8] =
                *(const half8*)&stage[e*520 + j*8];
        }
        __syncthreads();
    }
}

// ---------------------------------------------------------------------------
// K3b: per-src-node gather-reduce + FUSED combine. Block = 1 node, 128 thr.
// vbuf [slot][128][4] -> 1 half4/edge; Ych [node][128][16] -> half8+half4.
// ---------------------------------------------------------------------------
__global__ __launch_bounds__(128) void scatter_combine(
    const int* __restrict__ offs, const int* __restrict__ ends,
    const int* __restrict__ sdst, const f16* __restrict__ vbuf,
    const f16* __restrict__ Ych,
    f16* __restrict__ pre, int n0, int VC)
{
    const int s = n0 + blockIdx.x;
    const int h = threadIdx.x;
    const int pbase = offs[n0];
    const int p0 = offs[s], p1 = ends[s];

    float ps[10];
    #pragma unroll
    for (int c = 0; c < 10; c++) ps[c] = 0.f;

    for (int p = p0; p < p1; p++) {
        int sl = p - pbase;
        int d  = sdst[p];
        half4 v4 = *(const half4*)&vbuf[(size_t)sl*512 + h*4];
        const f16* yr = Ych + (size_t)d*2048 + h*16;
        half8 ya = *(const half8*)yr;
        half4 yb = *(const half4*)(yr + 8);
        float va = (float)v4[0], vb = (float)v4[1], vc = (float)v4[2];
        ps[0] = fmaf(va, (float)ya[0], ps[0]);
        ps[1] = fmaf(vb, (float)ya[1], ps[1]);
        ps[2] = fmaf(vb, (float)ya[2], ps[2]);
        ps[3] = fmaf(vb, (float)ya[3], ps[3]);
        ps[4] = fmaf(vc, (float)ya[4], ps[4]);
        ps[5] = fmaf(vc, (float)ya[5], ps[5]);
        ps[6] = fmaf(vc, (float)ya[6], ps[6]);
        ps[7] = fmaf(vc, (float)ya[7], ps[7]);
        ps[8] = fmaf(vc, (float)yb[0], ps[8]);
        ps[9] = fmaf(vc, (float)yb[1], ps[9]);
    }

    // ---- fused combine: T = M@Y + Y@M, decompose, normalize ----
    const f16* ysr = Ych + (size_t)s*2048 + h*16;
    half8 sa = *(const half8*)ysr;
    half4 sb = *(const half4*)(ysr + 8);
    float yI  = (float)sa[0];
    float ya0 = (float)sa[1], ya1 = (float)sa[2], ya2 = (float)sa[3];
    float ys00 = (float)sa[4], ys11 = (float)sa[5], ys22 = (float)sa[6];
    float ys01 = (float)sa[7], ys02 = (float)sb[0], ys12 = (float)sb[1];

    float M[3][3] = {
        { ps[0] + ps[4],  ps[7] - ps[3],  ps[8] + ps[2] },
        { ps[7] + ps[3],  ps[0] + ps[5],  ps[9] - ps[1] },
        { ps[8] - ps[2],  ps[9] + ps[1],  ps[0] + ps[6] } };
    float Y[3][3] = {
        { yI + ys00,  ys01 - ya2, ys02 + ya1 },
        { ys01 + ya2, yI + ys11,  ys12 - ya0 },
        { ys02 - ya1, ys12 + ya0, yI + ys22  } };

    float T[3][3];
    #pragma unroll
    for (int r = 0; r < 3; r++)
        #pragma unroll
        for (int c = 0; c < 3; c++) {
            float acc = 0.f;
            #pragma unroll
            for (int k = 0; k < 3; k++)
                acc += M[r][k] * Y[k][c] + Y[r][k] * M[k][c];
            T[r][c] = acc;
        }

    float tr3 = (T[0][0] + T[1][1] + T[2][2]) * (1.0f / 3.0f);
    float nsq = 0.f;
    #pragma unroll
    for (int r = 0; r < 3; r++)
        #pragma unroll
        for (int c = 0; c < 3; c++) nsq = fmaf(T[r][c], T[r][c], nsq);
    float inv = 1.0f / (nsq + 1.0f);

    const size_t idx = (size_t)s * HD + h;
    pre[0*(size_t)NH + idx] = (f16)(tr3 * inv);
    pre[1*(size_t)NH + idx] = (f16)(0.5f * (T[2][1] - T[1][2]) * inv);
    pre[2*(size_t)NH + idx] = (f16)(0.5f * (T[0][2] - T[2][0]) * inv);
    pre[3*(size_t)NH + idx] = (f16)(0.5f * (T[1][0] - T[0][1]) * inv);
    pre[4*(size_t)NH + idx] = (f16)((T[0][0] - tr3) * inv);
    pre[5*(size_t)NH + idx] = (f16)((T[1][1] - tr3) * inv);
    pre[6*(size_t)NH + idx] = (f16)((T[2][2] - tr3) * inv);
    pre[7*(size_t)NH + idx] = (f16)(0.5f * (T[0][1] + T[1][0]) * inv);
    pre[8*(size_t)NH + idx] = (f16)(0.5f * (T[0][2] + T[2][0]) * inv);
    pre[9*(size_t)NH + idx] = (f16)(0.5f * (T[1][2] + T[2][1]) * inv);
}

// ---------------------------------------------------------------------------
// K6: dX from postmix fields (f16 plane-major); out = Xn + dX + dX@dX
// ---------------------------------------------------------------------------
__global__ __launch_bounds__(256) void final_out(const f16* __restrict__ post,
                                                 const float* __restrict__ X,
                                                 float* __restrict__ out) {
    int idx = blockIdx.x * 256 + threadIdx.x;
    if (idx >= NH) return;

    float dI  = (float)post[0*(size_t)NH + idx];
    float da0 = (float)post[1*(size_t)NH + idx], da1 = (float)post[2*(size_t)NH + idx], da2 = (float)post[3*(size_t)NH + idx];
    float ds00 = (float)post[4*(size_t)NH + idx], ds11 = (float)post[5*(size_t)NH + idx], ds22 = (float)post[6*(size_t)NH + idx];
    float ds01 = (float)post[7*(size_t)NH + idx], ds02 = (float)post[8*(size_t)NH + idx], ds12 = (float)post[9*(size_t)NH + idx];

    float D[3][3] = {
        { dI + ds00,  ds01 - da2, ds02 + da1 },
        { ds01 + da2, dI + ds11,  ds12 - da0 },
        { ds02 - da1, ds12 + da0, dI + ds22  } };

    const float* xp = X + (size_t)idx * 9;
    float x[9];
    #pragma unroll
    for (int i = 0; i < 9; i++) x[i] = xp[i];
    float nsq = 0.f;
    #pragma unroll
    for (int i = 0; i < 9; i++) nsq = fmaf(x[i], x[i], nsq);
    float inv = 1.0f / (nsq + 1.0f);

    float* op = out + (size_t)idx * 9;
    #pragma unroll
    for (int r = 0; r < 3; r++)
        #pragma unroll
        for (int c = 0; c < 3; c++) {
            float p = 0.f;
            #pragma unroll
            for (int k = 0; k < 3; k++) p = fmaf(D[r][k], D[k][c], p);
            op[r*3 + c] = x[r*3 + c] * inv + D[r][c] + p;
        }
}

// ---------------------------------------------------------------------------
extern "C" void kernel_launch(void* const* d_in, const int* in_sizes, int n_in,
                              void* d_out, int out_size, void* d_ws, size_t ws_size,
                              hipStream_t stream) {
    const float* X       = (const float*)d_in[0];
    const float* charges = (const float*)d_in[1];
    const float* ew      = (const float*)d_in[2];
    const float* ea      = (const float*)d_in[3];
    const float* W1      = (const float*)d_in[4];
    const float* b1      = (const float*)d_in[5];
    const float* W2      = (const float*)d_in[6];
    const float* b2      = (const float*)d_in[7];
    const float* W3      = (const float*)d_in[8];
    const float* b3      = (const float*)d_in[9];
    const float* Wt      = (const float*)d_in[10];
    const int*   eidx    = (const int*)d_in[11];
    float* out = (float*)d_out;

    f16*   posth = (f16*)d_ws;                      // post (mix2 out, f16): 25.6 MB
    f16*   fh16  = posth + (size_t)10 * NH;         // comp (f16), then preh: 25.6 MB
    f16*   ych   = fh16 + (size_t)10 * NH;          // [NND][128][16] f16: 41 MB
    f16*   w1t   = ych + (size_t)NND * 2048;
    f16*   w2t   = w1t + 128*64;
    f16*   w3t   = w2t + 256*128;
    f16*   wtT   = w3t + 384*256;                   // [6][128][128] f16
    int*   hist   = (int*)(wtT + 6*128*128);
    int*   offs   = hist + NND;
    int*   cursor = offs + NND;                     // run-end after scatter
    int*   perm   = cursor + NND;
    int*   ssrc   = perm + NE;
    int*   sdst   = ssrc + NE;
    f16*   vbuf   = (f16*)(sdst + NE);              // [VC][128][4] f16, chunked

    // choose chunk count: need VC*(512+256)*2 bytes after 'vbuf'
    size_t used = (size_t)((char*)vbuf - (char*)d_ws);
    int Q, VC;
    if      (used + (size_t)160000 * 1536 <= ws_size) { Q = 1; VC = 160000; }
    else if (used + (size_t) 84480 * 1536 <= ws_size) { Q = 2; VC = 84480;  }
    else if (used + (size_t) 48000 * 1536 <= ws_size) { Q = 4; VC = 48000;  }
    else                                              { Q = 8; VC = 24320;  }
    f16* x2b = vbuf + (size_t)VC * 512;             // [VC][256]

    hipMemsetAsync(hist, 0, NND * sizeof(int), stream);

    w_prep<<<928, 256, 0, stream>>>(W1, W2, W3, Wt, w1t, w2t, w3t, wtT);
    node_prep<<<NH / 256, 256, 0, stream>>>(X, fh16);

    hist_kernel<<<(NE + 255) / 256, 256, 0, stream>>>(eidx, hist);
    scan_kernel<<<1, 1024, 0, stream>>>(hist, offs, cursor);
    scatter_kernel<<<(NE + 255) / 256, 256, 0, stream>>>(eidx, cursor, perm, ssrc, sdst);

    dim3 gmix((6 * NND + 63) / 64, 3);
    // mix #1: comp -> Ych (f16 channel-major) only
    mix_mfma<<<gmix, 256, 0, stream>>>(fh16, wtT, ych, posth, 0, 1, 2, 1, 0);

    const int nodesPer = NND / Q;
    for (int q = 0; q < Q; q++) {
        int n0 = q * nodesPer, n1 = n0 + nodesPer;
        int nb = VC / 64;
        edge_gemm12<<<nb, 256, 0, stream>>>(ea, charges, offs, perm, ssrc, sdst,
                                            w1t, b1, w2t, b2, x2b, n0, n1);
        edge_gemm3<<<nb, 256, 0, stream>>>(ew, offs, perm, x2b, w3t, b3,
                                           vbuf, n0, n1);
        scatter_combine<<<nodesPer, 128, 0, stream>>>(offs, cursor, sdst, vbuf,
                                                      ych, fh16, n0, VC);
    }

    // mix #2: preh -> posth (f16 plane-major)
    mix_mfma<<<gmix, 256, 0, stream>>>(fh16, wtT, ych, posth, 3, 4, 5, 0, 1);

    final_out<<<NH / 256, 256, 0, stream>>>(posth, X, out);
}

// Round 13
// 509.042 us; speedup vs baseline: 1.1029x; 1.1029x over previous
//
#include <hip/hip_runtime.h>
#include <math.h>

#define NND 10000
#define NE  160000
#define HD  128
#define NH  (NND*HD)   // 1,280,000

typedef _Float16 f16;
typedef _Float16 half8 __attribute__((ext_vector_type(8)));
typedef _Float16 half4 __attribute__((ext_vector_type(4)));
typedef float floatx4 __attribute__((ext_vector_type(4)));

__device__ __forceinline__ float silu_f(float v) {
    return v * (1.0f / (1.0f + __expf(-v)));
}

// ---------------------------------------------------------------------------
// K0: weights -> fp16, transposed to [N][K] for contiguous fragment loads.
// ---------------------------------------------------------------------------
__global__ __launch_bounds__(256) void w_prep(const float* __restrict__ W1,
                                              const float* __restrict__ W2,
                                              const float* __restrict__ W3,
                                              const float* __restrict__ Wt,
                                              f16* __restrict__ w1t,
                                              f16* __restrict__ w2t,
                                              f16* __restrict__ w3t,
                                              f16* __restrict__ wtT) {
    int id = blockIdx.x * 256 + threadIdx.x;
    if (id < 128*64) { int n = id >> 6, k = id & 63;  w1t[id] = (f16)W1[k*128 + n]; return; }
    id -= 128*64;
    if (id < 256*128) { int n = id >> 7, k = id & 127; w2t[id] = (f16)W2[k*256 + n]; return; }
    id -= 256*128;
    if (id < 384*256) { int n = id >> 8, k = id & 255; w3t[id] = (f16)W3[k*384 + n]; return; }
    id -= 384*256;
    if (id < 6*128*128) {
        int wi = id >> 14, rem = id & 16383;
        int n = rem >> 7, k = rem & 127;
        wtT[(size_t)wi*16384 + n*128 + k] = (f16)Wt[(size_t)wi*16384 + k*128 + n];
    }
}

// ---------------------------------------------------------------------------
// Counting sort of edges by src: histogram -> scan -> scatter
// ---------------------------------------------------------------------------
__global__ __launch_bounds__(256) void hist_kernel(const int* __restrict__ eidx,
                                                   int* __restrict__ hist) {
    int e = blockIdx.x * 256 + threadIdx.x;
    if (e < NE) atomicAdd(&hist[eidx[e]], 1);
}

__global__ __launch_bounds__(1024) void scan_kernel(const int* __restrict__ hist,
                                                    int* __restrict__ offs,
                                                    int* __restrict__ cursor) {
    __shared__ int sums[1024];
    int t = threadIdx.x;
    int base = t * 10;
    int loc[10]; int s = 0;
    #pragma unroll
    for (int i = 0; i < 10; i++) {
        int v = (base + i < NND) ? hist[base + i] : 0;
        loc[i] = s; s += v;
    }
    sums[t] = s;
    __syncthreads();
    for (int off = 1; off < 1024; off <<= 1) {
        int v = (t >= off) ? sums[t - off] : 0;
        __syncthreads();
        sums[t] += v;
        __syncthreads();
    }
    int basesum = (t > 0) ? sums[t - 1] : 0;
    #pragma unroll
    for (int i = 0; i < 10; i++)
        if (base + i < NND) { offs[base + i] = basesum + loc[i]; cursor[base + i] = basesum + loc[i]; }
}

__global__ __launch_bounds__(256) void scatter_kernel(const int* __restrict__ eidx,
                                                      int* __restrict__ cursor,
                                                      int* __restrict__ perm,
                                                      int* __restrict__ ssrc,
                                                      int* __restrict__ sdst) {
    int e = blockIdx.x * 256 + threadIdx.x;
    if (e >= NE) return;
    int s = eidx[e], d = eidx[NE + e];
    int pos = atomicAdd(&cursor[s], 1);
    perm[pos] = e; ssrc[pos] = s; sdst[pos] = d;
}

// ---------------------------------------------------------------------------
// K1: normalize X, decompose into 10 scalar fields [f][n][h] (f16)
// ---------------------------------------------------------------------------
__global__ __launch_bounds__(256) void node_prep(const float* __restrict__ X,
                                                 f16* __restrict__ comp) {
    int idx = blockIdx.x * 256 + threadIdx.x;
    if (idx >= NH) return;
    const float* xp = X + (size_t)idx * 9;
    float x[9];
    #pragma unroll
    for (int i = 0; i < 9; i++) x[i] = xp[i];
    float nsq = 0.f;
    #pragma unroll
    for (int i = 0; i < 9; i++) nsq = fmaf(x[i], x[i], nsq);
    float inv = 1.0f / (nsq + 1.0f);
    #pragma unroll
    for (int i = 0; i < 9; i++) x[i] *= inv;

    float I0  = (x[0] + x[4] + x[8]) * (1.0f / 3.0f);
    float a0  = 0.5f * (x[7] - x[5]);
    float a1  = 0.5f * (x[2] - x[6]);
    float a2  = 0.5f * (x[3] - x[1]);
    float s00 = x[0] - I0;
    float s11 = x[4] - I0;
    float s22 = x[8] - I0;
    float s01 = 0.5f * (x[1] + x[3]);
    float s02 = 0.5f * (x[2] + x[6]);
    float s12 = 0.5f * (x[5] + x[7]);

    comp[0*NH + idx] = (f16)I0;
    comp[1*NH + idx] = (f16)a0;  comp[2*NH + idx] = (f16)a1;  comp[3*NH + idx] = (f16)a2;
    comp[4*NH + idx] = (f16)s00; comp[5*NH + idx] = (f16)s11; comp[6*NH + idx] = (f16)s22;
    comp[7*NH + idx] = (f16)s01; comp[8*NH + idx] = (f16)s02; comp[9*NH + idx] = (f16)s12;
}

// ---------------------------------------------------------------------------
// K2: channel-mix GEMM via fp16 MFMA. Writes f16 plane-major only (coalesced).
// ---------------------------------------------------------------------------
__global__ __launch_bounds__(256) void mix_mfma(const f16* __restrict__ A,
                                                const f16* __restrict__ WtT,
                                                f16* __restrict__ Cp,
                                                int w0, int w1, int w2) {
    const int g = blockIdx.y;
    const int baseRow = (g == 0) ? 0   : (g == 1 ? NND   : 4*NND);
    const int Mg      = (g == 0) ? NND : (g == 1 ? 3*NND : 6*NND);
    const int row0 = blockIdx.x * 64;
    if (row0 >= Mg) return;
    const int wi = (g == 0) ? w0 : (g == 1 ? w1 : w2);
    const f16* B = WtT + (size_t)wi * 128 * 128;

    __shared__ f16 As[64 * 136];

    const int t = threadIdx.x;
    const int l = t & 63, wid = t >> 6, lr = l & 15, lh = l >> 4;

    #pragma unroll
    for (int i = 0; i < 4; i++) {
        int id = t + 256 * i;
        int r = id >> 4, ch = id & 15;
        int rr = row0 + r; if (rr >= Mg) rr = Mg - 1;
        *(half8*)&As[r*136 + ch*8] =
            *(const half8*)&A[((size_t)baseRow + rr) * HD + ch*8];
    }
    __syncthreads();

    floatx4 acc[8];
    #pragma unroll
    for (int n = 0; n < 8; n++) acc[n] = (floatx4)0.0f;

    #pragma unroll
    for (int k0 = 0; k0 < 128; k0 += 32) {
        half8 a = *(const half8*)&As[(wid*16 + lr)*136 + k0 + lh*8];
        #pragma unroll
        for (int n = 0; n < 8; n++) {
            half8 b = *(const half8*)&B[(size_t)(n*16 + lr)*128 + k0 + lh*8];
            acc[n] = __builtin_amdgcn_mfma_f32_16x16x32_f16(a, b, acc[n], 0, 0, 0);
        }
    }

    #pragma unroll
    for (int n = 0; n < 8; n++) {
        #pragma unroll
        for (int r = 0; r < 4; r++) {
            int gl = row0 + wid*16 + lh*4 + r;
            if (gl < Mg) {
                size_t grow = (size_t)baseRow + gl;
                int col = n*16 + lr;
                Cp[grow * HD + col] = (f16)acc[n][r];
            }
        }
    }
}

// ---------------------------------------------------------------------------
// K2b: plane-major [10][NND][128] -> channel-major [node][128][16].
// Thread <-> (node,col): 10 coalesced plane loads, one contiguous 32B store.
// ---------------------------------------------------------------------------
__global__ __launch_bounds__(256) void y_transpose(const f16* __restrict__ ypl,
                                                   f16* __restrict__ ych) {
    int id = blockIdx.x * 256 + threadIdx.x;
    if (id >= NH) return;
    int col = id & 127, node = id >> 7;
    f16 v[16];
    #pragma unroll
    for (int p = 0; p < 10; p++)
        v[p] = ypl[(size_t)p*NH + (size_t)node*HD + col];
    #pragma unroll
    for (int p = 10; p < 16; p++) v[p] = (f16)0;
    f16* dst = ych + (size_t)node*2048 + col*16;
    *(half8*)dst       = *(half8*)&v[0];
    *(half8*)(dst + 8) = *(half8*)&v[8];
}

// ---------------------------------------------------------------------------
// K3a: fused layers 1+2 (proven config: bounds(256,4), 33 KB pool).
// ---------------------------------------------------------------------------
__global__ __launch_bounds__(256, 4) void edge_gemm12(
    const float* __restrict__ edge_attr, const float* __restrict__ charges,
    const int* __restrict__ offs,
    const int* __restrict__ perm, const int* __restrict__ ssrc, const int* __restrict__ sdst,
    const f16* __restrict__ W1t, const float* __restrict__ b1,
    const f16* __restrict__ W2t, const float* __restrict__ b2,
    f16* __restrict__ x2b, int n0, int n1)
{
    __shared__ __align__(16) char pool[33280];
    f16* x0s  = (f16*)pool;                // 64*72*2  = 9216
    f16* x1s  = (f16*)(pool + 9216);       // 64*140*2 = 17920 (ends 27136)
    f16* x2st = (f16*)pool;                // 64*260*2 = 33280 (aliases, post-MFMA)
    __shared__ int srcS[64], dstS[64], permS[64];

    const int pbase = offs[n0];
    const int pend  = (n1 >= NND) ? NE : offs[n1];
    const int eb    = blockIdx.x * 64;
    if (pbase + eb >= pend) return;

    const int t = threadIdx.x;
    const int l = t & 63, wid = t >> 6, lr = l & 15, lh = l >> 4;

    if (t < 64) {
        int pe = pbase + eb + t;
        if (pe > NE - 1) pe = NE - 1;
        permS[t] = perm[pe];
        srcS[t]  = ssrc[pe];
        dstS[t]  = sdst[pe];
    }
    __syncthreads();

    // gather-stage: [attr(32) | charges[src](16) | charges[dst](16)]
    {
        int e = t >> 2, q = t & 3;
        #pragma unroll
        for (int jj = 0; jj < 2; jj++) {
            int j = q + jj*4;
            float4 va = *(const float4*)&edge_attr[(size_t)permS[e]*32 + j*4];
            half4 hv; hv[0]=(f16)va.x; hv[1]=(f16)va.y; hv[2]=(f16)va.z; hv[3]=(f16)va.w;
            *(half4*)&x0s[e*72 + j*4] = hv;
        }
        int node = (q < 2) ? srcS[e] : dstS[e];
        int qq   = (q < 2) ? q : (q - 2);
        int cb   = (q < 2) ? 32 : 48;
        #pragma unroll
        for (int jj = 0; jj < 2; jj++) {
            int j = qq + jj*2;
            float4 vc = *(const float4*)&charges[(size_t)node*16 + j*4];
            half4 hv; hv[0]=(f16)vc.x; hv[1]=(f16)vc.y; hv[2]=(f16)vc.z; hv[3]=(f16)vc.w;
            *(half4*)&x0s[e*72 + cb + j*4] = hv;
        }
    }
    __syncthreads();

    // ---- layer 1: [64 e][64 k] @ W1t[128][64] -> x1s (LDS) ----
    {
        floatx4 acc[2][4];
        #pragma unroll
        for (int n = 0; n < 2; n++)
            #pragma unroll
            for (int m = 0; m < 4; m++) acc[n][m] = (floatx4)0.0f;

        #pragma unroll
        for (int k0 = 0; k0 < 64; k0 += 32) {
            half8 a[4];
            #pragma unroll
            for (int m = 0; m < 4; m++)
                a[m] = *(const half8*)&x0s[(m*16 + lr)*72 + k0 + lh*8];
            #pragma unroll
            for (int n = 0; n < 2; n++) {
                half8 b = *(const half8*)&W1t[(size_t)(wid*32 + n*16 + lr)*64 + k0 + lh*8];
                #pragma unroll
                for (int m = 0; m < 4; m++)
                    acc[n][m] = __builtin_amdgcn_mfma_f32_16x16x32_f16(a[m], b, acc[n][m], 0, 0, 0);
            }
        }
        #pragma unroll
        for (int n = 0; n < 2; n++) {
            int col = wid*32 + n*16 + lr;
            float bb = b1[col];
            #pragma unroll
            for (int m = 0; m < 4; m++)
                #pragma unroll
                for (int r = 0; r < 4; r++)
                    x1s[(m*16 + lh*4 + r)*140 + col] = (f16)silu_f(acc[n][m][r] + bb);
        }
    }
    __syncthreads();

    // ---- layer 2: x1s[64][128] @ W2t[256][128] -> x2st (LDS) -> global ----
    {
        floatx4 acc[4][4];
        #pragma unroll
        for (int n = 0; n < 4; n++)
            #pragma unroll
            for (int m = 0; m < 4; m++) acc[n][m] = (floatx4)0.0f;

        #pragma unroll
        for (int k0 = 0; k0 < 128; k0 += 32) {
            half8 a[4];
            #pragma unroll
            for (int m = 0; m < 4; m++)
                a[m] = *(const half8*)&x1s[(m*16 + lr)*140 + k0 + lh*8];
            #pragma unroll
            for (int n = 0; n < 4; n++) {
                half8 b = *(const half8*)&W2t[(size_t)(wid*64 + n*16 + lr)*128 + k0 + lh*8];
                #pragma unroll
                for (int m = 0; m < 4; m++)
                    acc[n][m] = __builtin_amdgcn_mfma_f32_16x16x32_f16(a[m], b, acc[n][m], 0, 0, 0);
            }
        }
        __syncthreads();            // all x0s/x1s reads done before aliasing x2st
        #pragma unroll
        for (int n = 0; n < 4; n++) {
            int col = wid*64 + n*16 + lr;
            float bb = b2[col];
            #pragma unroll
            for (int m = 0; m < 4; m++)
                #pragma unroll
                for (int r = 0; r < 4; r++)
                    x2st[(m*16 + lh*4 + r)*260 + col] = (f16)silu_f(acc[n][m][r] + bb);
        }
    }
    __syncthreads();

    #pragma unroll
    for (int i = 0; i < 8; i++) {
        int c = t + 256 * i;
        int e = c >> 5, j = c & 31;
        *(half8*)&x2b[(size_t)(eb + e)*256 + j*8] = *(const half8*)&x2st[e*260 + j*8];
    }
}

// ---------------------------------------------------------------------------
// K3a': layer 3. x2 [VC][256] -> vbuf [slot][128][4] f16 ((I,A,S,pad) per ch),
// cutoff-scaled. Full N=384, acc[6][4]; two-phase 32-row twisted staging.
// ---------------------------------------------------------------------------
__global__ __launch_bounds__(256) void edge_gemm3(
    const float* __restrict__ edge_weight,
    const int* __restrict__ offs, const int* __restrict__ perm,
    const f16* __restrict__ x2b,
    const f16* __restrict__ W3t, const float* __restrict__ b3,
    f16* __restrict__ vbuf, int n0, int n1)
{
    __shared__ __align__(16) char pool[33280];
    f16* As    = (f16*)pool;               // 64*136*2 = 17408
    f16* stage = (f16*)pool;               // 32*520*2 = 33280 (aliases, post-MFMA)
    __shared__ float Cs[64];

    const int pbase = offs[n0];
    const int pend  = (n1 >= NND) ? NE : offs[n1];
    const int eb    = blockIdx.x * 64;
    if (pbase + eb >= pend) return;

    const int t = threadIdx.x;
    const int l = t & 63, wid = t >> 6, lr = l & 15, lh = l >> 4;

    if (t < 64) {
        int pe = pbase + eb + t;
        if (pe > NE - 1) pe = NE - 1;
        float w = edge_weight[perm[pe]];
        float c = 0.5f * (cosf(w * (float)(M_PI / 4.5)) + 1.0f);
        Cs[t] = (w < 4.5f) ? c : 0.0f;
    }

    floatx4 acc[6][4];
    #pragma unroll
    for (int n = 0; n < 6; n++)
        #pragma unroll
        for (int m = 0; m < 4; m++) acc[n][m] = (floatx4)0.0f;

    #pragma unroll
    for (int kb = 0; kb < 2; kb++) {
        __syncthreads();
        #pragma unroll
        for (int i = 0; i < 4; i++) {
            int id = t + 256 * i;
            int r = id >> 4, c = id & 15;
            *(half8*)&As[r*136 + c*8] =
                *(const half8*)&x2b[(size_t)(eb + r)*256 + kb*128 + c*8];
        }
        __syncthreads();

        #pragma unroll
        for (int k0 = 0; k0 < 128; k0 += 32) {
            half8 a[4];
            #pragma unroll
            for (int m = 0; m < 4; m++)
                a[m] = *(const half8*)&As[(m*16 + lr)*136 + k0 + lh*8];
            #pragma unroll
            for (int n = 0; n < 6; n++) {
                half8 b = *(const half8*)&W3t[(size_t)(wid*96 + n*16 + lr)*256 + kb*128 + k0 + lh*8];
                #pragma unroll
                for (int m = 0; m < 4; m++)
                    acc[n][m] = __builtin_amdgcn_mfma_f32_16x16x32_f16(a[m], b, acc[n][m], 0, 0, 0);
            }
        }
    }
    __syncthreads();                 // As reads done before stage overwrite

    #pragma unroll
    for (int ph = 0; ph < 2; ph++) {
        #pragma unroll
        for (int n = 0; n < 6; n++) {
            int col = wid*96 + n*16 + lr;
            int gg = col >> 7, hc = col & 127;
            float bb = b3[col];
            #pragma unroll
            for (int mm = 0; mm < 2; mm++) {
                int m = ph*2 + mm;
                #pragma unroll
                for (int r = 0; r < 4; r++) {
                    int e  = mm*16 + lh*4 + r;          // row within phase
                    int ge = m*16 + lh*4 + r;           // global row (for Cs)
                    stage[e*520 + hc*4 + gg] = (f16)(silu_f(acc[n][m][r] + bb) * Cs[ge]);
                }
            }
        }
        __syncthreads();
        #pragma unroll
        for (int i = 0; i < 8; i++) {
            int c = t + 256 * i;              // 0..2047
            int e = c >> 6, j = c & 63;       // 32 rows x 64 half8s
            *(half8*)&vbuf[(size_t)(eb + ph*32 + e)*512 + j*8] =
                *(const half8*)&stage[e*520 + j*8];
        }
        __syncthreads();
    }
}

// ---------------------------------------------------------------------------
// K3b: per-src-node gather-reduce + FUSED combine. Block = 1 node, 128 thr.
// vbuf [slot][128][4] -> 1 half4/edge; Ych [node][128][16] -> half8+half4.
// ---------------------------------------------------------------------------
__global__ __launch_bounds__(128) void scatter_combine(
    const int* __restrict__ offs, const int* __restrict__ ends,
    const int* __restrict__ sdst, const f16* __restrict__ vbuf,
    const f16* __restrict__ Ych,
    f16* __restrict__ pre, int n0, int VC)
{
    const int s = n0 + blockIdx.x;
    const int h = threadIdx.x;
    const int pbase = offs[n0];
    const int p0 = offs[s], p1 = ends[s];

    float ps[10];
    #pragma unroll
    for (int c = 0; c < 10; c++) ps[c] = 0.f;

    for (int p = p0; p < p1; p++) {
        int sl = p - pbase;
        int d  = sdst[p];
        half4 v4 = *(const half4*)&vbuf[(size_t)sl*512 + h*4];
        const f16* yr = Ych + (size_t)d*2048 + h*16;
        half8 ya = *(const half8*)yr;
        half4 yb = *(const half4*)(yr + 8);
        float va = (float)v4[0], vb = (float)v4[1], vc = (float)v4[2];
        ps[0] = fmaf(va, (float)ya[0], ps[0]);
        ps[1] = fmaf(vb, (float)ya[1], ps[1]);
        ps[2] = fmaf(vb, (float)ya[2], ps[2]);
        ps[3] = fmaf(vb, (float)ya[3], ps[3]);
        ps[4] = fmaf(vc, (float)ya[4], ps[4]);
        ps[5] = fmaf(vc, (float)ya[5], ps[5]);
        ps[6] = fmaf(vc, (float)ya[6], ps[6]);
        ps[7] = fmaf(vc, (float)ya[7], ps[7]);
        ps[8] = fmaf(vc, (float)yb[0], ps[8]);
        ps[9] = fmaf(vc, (float)yb[1], ps[9]);
    }

    // ---- fused combine: T = M@Y + Y@M, decompose, normalize ----
    const f16* ysr = Ych + (size_t)s*2048 + h*16;
    half8 sa = *(const half8*)ysr;
    half4 sb = *(const half4*)(ysr + 8);
    float yI  = (float)sa[0];
    float ya0 = (float)sa[1], ya1 = (float)sa[2], ya2 = (float)sa[3];
    float ys00 = (float)sa[4], ys11 = (float)sa[5], ys22 = (float)sa[6];
    float ys01 = (float)sa[7], ys02 = (float)sb[0], ys12 = (float)sb[1];

    float M[3][3] = {
        { ps[0] + ps[4],  ps[7] - ps[3],  ps[8] + ps[2] },
        { ps[7] + ps[3],  ps[0] + ps[5],  ps[9] - ps[1] },
        { ps[8] - ps[2],  ps[9] + ps[1],  ps[0] + ps[6] } };
    float Y[3][3] = {
        { yI + ys00,  ys01 - ya2, ys02 + ya1 },
        { ys01 + ya2, yI + ys11,  ys12 - ya0 },
        { ys02 - ya1, ys12 + ya0, yI + ys22  } };

    float T[3][3];
    #pragma unroll
    for (int r = 0; r < 3; r++)
        #pragma unroll
        for (int c = 0; c < 3; c++) {
            float acc = 0.f;
            #pragma unroll
            for (int k = 0; k < 3; k++)
                acc += M[r][k] * Y[k][c] + Y[r][k] * M[k][c];
            T[r][c] = acc;
        }

    float tr3 = (T[0][0] + T[1][1] + T[2][2]) * (1.0f / 3.0f);
    float nsq = 0.f;
    #pragma unroll
    for (int r = 0; r < 3; r++)
        #pragma unroll
        for (int c = 0; c < 3; c++) nsq = fmaf(T[r][c], T[r][c], nsq);
    float inv = 1.0f / (nsq + 1.0f);

    const size_t idx = (size_t)s * HD + h;
    pre[0*(size_t)NH + idx] = (f16)(tr3 * inv);
    pre[1*(size_t)NH + idx] = (f16)(0.5f * (T[2][1] - T[1][2]) * inv);
    pre[2*(size_t)NH + idx] = (f16)(0.5f * (T[0][2] - T[2][0]) * inv);
    pre[3*(size_t)NH + idx] = (f16)(0.5f * (T[1][0] - T[0][1]) * inv);
    pre[4*(size_t)NH + idx] = (f16)((T[0][0] - tr3) * inv);
    pre[5*(size_t)NH + idx] = (f16)((T[1][1] - tr3) * inv);
    pre[6*(size_t)NH + idx] = (f16)((T[2][2] - tr3) * inv);
    pre[7*(size_t)NH + idx] = (f16)(0.5f * (T[0][1] + T[1][0]) * inv);
    pre[8*(size_t)NH + idx] = (f16)(0.5f * (T[0][2] + T[2][0]) * inv);
    pre[9*(size_t)NH + idx] = (f16)(0.5f * (T[1][2] + T[2][1]) * inv);
}

// ---------------------------------------------------------------------------
// K6: dX from postmix fields (f16 plane-major); out = Xn + dX + dX@dX
// ---------------------------------------------------------------------------
__global__ __launch_bounds__(256) void final_out(const f16* __restrict__ post,
                                                 const float* __restrict__ X,
                                                 float* __restrict__ out) {
    int idx = blockIdx.x * 256 + threadIdx.x;
    if (idx >= NH) return;

    float dI  = (float)post[0*(size_t)NH + idx];
    float da0 = (float)post[1*(size_t)NH + idx], da1 = (float)post[2*(size_t)NH + idx], da2 = (float)post[3*(size_t)NH + idx];
    float ds00 = (float)post[4*(size_t)NH + idx], ds11 = (float)post[5*(size_t)NH + idx], ds22 = (float)post[6*(size_t)NH + idx];
    float ds01 = (float)post[7*(size_t)NH + idx], ds02 = (float)post[8*(size_t)NH + idx], ds12 = (float)post[9*(size_t)NH + idx];

    float D[3][3] = {
        { dI + ds00,  ds01 - da2, ds02 + da1 },
        { ds01 + da2, dI + ds11,  ds12 - da0 },
        { ds02 - da1, ds12 + da0, dI + ds22  } };

    const float* xp = X + (size_t)idx * 9;
    float x[9];
    #pragma unroll
    for (int i = 0; i < 9; i++) x[i] = xp[i];
    float nsq = 0.f;
    #pragma unroll
    for (int i = 0; i < 9; i++) nsq = fmaf(x[i], x[i], nsq);
    float inv = 1.0f / (nsq + 1.0f);

    float* op = out + (size_t)idx * 9;
    #pragma unroll
    for (int r = 0; r < 3; r++)
        #pragma unroll
        for (int c = 0; c < 3; c++) {
            float p = 0.f;
            #pragma unroll
            for (int k = 0; k < 3; k++) p = fmaf(D[r][k], D[k][c], p);
            op[r*3 + c] = x[r*3 + c] * inv + D[r][c] + p;
        }
}

// ---------------------------------------------------------------------------
extern "C" void kernel_launch(void* const* d_in, const int* in_sizes, int n_in,
                              void* d_out, int out_size, void* d_ws, size_t ws_size,
                              hipStream_t stream) {
    const float* X       = (const float*)d_in[0];
    const float* charges = (const float*)d_in[1];
    const float* ew      = (const float*)d_in[2];
    const float* ea      = (const float*)d_in[3];
    const float* W1      = (const float*)d_in[4];
    const float* b1      = (const float*)d_in[5];
    const float* W2      = (const float*)d_in[6];
    const float* b2      = (const float*)d_in[7];
    const float* W3      = (const float*)d_in[8];
    const float* b3      = (const float*)d_in[9];
    const float* Wt      = (const float*)d_in[10];
    const int*   eidx    = (const int*)d_in[11];
    float* out = (float*)d_out;

    f16*   posth = (f16*)d_ws;                      // mix1 plane-major Y, later mix2 out: 25.6 MB
    f16*   fh16  = posth + (size_t)10 * NH;         // comp (f16), then preh: 25.6 MB
    f16*   ych   = fh16 + (size_t)10 * NH;          // [NND][128][16] f16: 41 MB
    f16*   w1t   = ych + (size_t)NND * 2048;
    f16*   w2t   = w1t + 128*64;
    f16*   w3t   = w2t + 256*128;
    f16*   wtT   = w3t + 384*256;                   // [6][128][128] f16
    int*   hist   = (int*)(wtT + 6*128*128);
    int*   offs   = hist + NND;
    int*   cursor = offs + NND;                     // run-end after scatter
    int*   perm   = cursor + NND;
    int*   ssrc   = perm + NE;
    int*   sdst   = ssrc + NE;
    f16*   vbuf   = (f16*)(sdst + NE);              // [VC][128][4] f16, chunked

    // choose chunk count: need VC*(512+256)*2 bytes after 'vbuf'
    size_t used = (size_t)((char*)vbuf - (char*)d_ws);
    int Q, VC;
    if      (used + (size_t)160000 * 1536 <= ws_size) { Q = 1; VC = 160000; }
    else if (used + (size_t) 84480 * 1536 <= ws_size) { Q = 2; VC = 84480;  }
    else if (used + (size_t) 48000 * 1536 <= ws_size) { Q = 4; VC = 48000;  }
    else                                              { Q = 8; VC = 24320;  }
    f16* x2b = vbuf + (size_t)VC * 512;             // [VC][256]

    hipMemsetAsync(hist, 0, NND * sizeof(int), stream);

    w_prep<<<928, 256, 0, stream>>>(W1, W2, W3, Wt, w1t, w2t, w3t, wtT);
    node_prep<<<NH / 256, 256, 0, stream>>>(X, fh16);

    hist_kernel<<<(NE + 255) / 256, 256, 0, stream>>>(eidx, hist);
    scan_kernel<<<1, 1024, 0, stream>>>(hist, offs, cursor);
    scatter_kernel<<<(NE + 255) / 256, 256, 0, stream>>>(eidx, cursor, perm, ssrc, sdst);

    dim3 gmix((6 * NND + 63) / 64, 3);
    // mix #1: comp -> plane-major Y (posth), then transpose to channel-major ych
    mix_mfma<<<gmix, 256, 0, stream>>>(fh16, wtT, posth, 0, 1, 2);
    y_transpose<<<NH / 256, 256, 0, stream>>>(posth, ych);

    const int nodesPer = NND / Q;
    for (int q = 0; q < Q; q++) {
        int n0 = q * nodesPer, n1 = n0 + nodesPer;
        int nb = VC / 64;
        edge_gemm12<<<nb, 256, 0, stream>>>(ea, charges, offs, perm, ssrc, sdst,
                                            w1t, b1, w2t, b2, x2b, n0, n1);
        edge_gemm3<<<nb, 256, 0, stream>>>(ew, offs, perm, x2b, w3t, b3,
                                           vbuf, n0, n1);
        scatter_combine<<<nodesPer, 128, 0, stream>>>(offs, cursor, sdst, vbuf,
                                                      ych, fh16, n0, VC);
    }

    // mix #2: preh -> posth (f16 plane-major)
    mix_mfma<<<gmix, 256, 0, stream>>>(fh16, wtT, posth, 3, 4, 5);

    final_out<<<NH / 256, 256, 0, stream>>>(posth, X, out);
}

// Round 14
// 432.915 us; speedup vs baseline: 1.2968x; 1.1758x over previous
//
#include <hip/hip_runtime.h>
#include <math.h>

#define NND 10000
#define NE  160000
#define HD  128
#define NH  (NND*HD)   // 1,280,000

typedef _Float16 f16;
typedef _Float16 half8 __attribute__((ext_vector_type(8)));
typedef _Float16 half4 __attribute__((ext_vector_type(4)));
typedef float floatx4 __attribute__((ext_vector_type(4)));

__device__ __forceinline__ float silu_f(float v) {
    return v * (1.0f / (1.0f + __expf(-v)));
}

// ---------------------------------------------------------------------------
// K0: weights -> fp16, transposed to [N][K] for contiguous fragment loads.
// ---------------------------------------------------------------------------
__global__ __launch_bounds__(256) void w_prep(const float* __restrict__ W1,
                                              const float* __restrict__ W2,
                                              const float* __restrict__ W3,
                                              const float* __restrict__ Wt,
                                              f16* __restrict__ w1t,
                                              f16* __restrict__ w2t,
                                              f16* __restrict__ w3t,
                                              f16* __restrict__ wtT) {
    int id = blockIdx.x * 256 + threadIdx.x;
    if (id < 128*64) { int n = id >> 6, k = id & 63;  w1t[id] = (f16)W1[k*128 + n]; return; }
    id -= 128*64;
    if (id < 256*128) { int n = id >> 7, k = id & 127; w2t[id] = (f16)W2[k*256 + n]; return; }
    id -= 256*128;
    if (id < 384*256) { int n = id >> 8, k = id & 255; w3t[id] = (f16)W3[k*384 + n]; return; }
    id -= 384*256;
    if (id < 6*128*128) {
        int wi = id >> 14, rem = id & 16383;
        int n = rem >> 7, k = rem & 127;
        wtT[(size_t)wi*16384 + n*128 + k] = (f16)Wt[(size_t)wi*16384 + k*128 + n];
    }
}

// ---------------------------------------------------------------------------
// Counting sort of edges by src: histogram -> scan -> scatter
// ---------------------------------------------------------------------------
__global__ __launch_bounds__(256) void hist_kernel(const int* __restrict__ eidx,
                                                   int* __restrict__ hist) {
    int e = blockIdx.x * 256 + threadIdx.x;
    if (e < NE) atomicAdd(&hist[eidx[e]], 1);
}

__global__ __launch_bounds__(1024) void scan_kernel(const int* __restrict__ hist,
                                                    int* __restrict__ offs,
                                                    int* __restrict__ cursor) {
    __shared__ int sums[1024];
    int t = threadIdx.x;
    int base = t * 10;
    int loc[10]; int s = 0;
    #pragma unroll
    for (int i = 0; i < 10; i++) {
        int v = (base + i < NND) ? hist[base + i] : 0;
        loc[i] = s; s += v;
    }
    sums[t] = s;
    __syncthreads();
    for (int off = 1; off < 1024; off <<= 1) {
        int v = (t >= off) ? sums[t - off] : 0;
        __syncthreads();
        sums[t] += v;
        __syncthreads();
    }
    int basesum = (t > 0) ? sums[t - 1] : 0;
    #pragma unroll
    for (int i = 0; i < 10; i++)
        if (base + i < NND) { offs[base + i] = basesum + loc[i]; cursor[base + i] = basesum + loc[i]; }
}

__global__ __launch_bounds__(256) void scatter_kernel(const int* __restrict__ eidx,
                                                      int* __restrict__ cursor,
                                                      int* __restrict__ perm,
                                                      int* __restrict__ ssrc,
                                                      int* __restrict__ sdst) {
    int e = blockIdx.x * 256 + threadIdx.x;
    if (e >= NE) return;
    int s = eidx[e], d = eidx[NE + e];
    int pos = atomicAdd(&cursor[s], 1);
    perm[pos] = e; ssrc[pos] = s; sdst[pos] = d;
}

// ---------------------------------------------------------------------------
// K1: normalize X, decompose into 10 scalar fields [f][n][h] (f16)
// ---------------------------------------------------------------------------
__global__ __launch_bounds__(256) void node_prep(const float* __restrict__ X,
                                                 f16* __restrict__ comp) {
    int idx = blockIdx.x * 256 + threadIdx.x;
    if (idx >= NH) return;
    const float* xp = X + (size_t)idx * 9;
    float x[9];
    #pragma unroll
    for (int i = 0; i < 9; i++) x[i] = xp[i];
    float nsq = 0.f;
    #pragma unroll
    for (int i = 0; i < 9; i++) nsq = fmaf(x[i], x[i], nsq);
    float inv = 1.0f / (nsq + 1.0f);
    #pragma unroll
    for (int i = 0; i < 9; i++) x[i] *= inv;

    float I0  = (x[0] + x[4] + x[8]) * (1.0f / 3.0f);
    float a0  = 0.5f * (x[7] - x[5]);
    float a1  = 0.5f * (x[2] - x[6]);
    float a2  = 0.5f * (x[3] - x[1]);
    float s00 = x[0] - I0;
    float s11 = x[4] - I0;
    float s22 = x[8] - I0;
    float s01 = 0.5f * (x[1] + x[3]);
    float s02 = 0.5f * (x[2] + x[6]);
    float s12 = 0.5f * (x[5] + x[7]);

    comp[0*NH + idx] = (f16)I0;
    comp[1*NH + idx] = (f16)a0;  comp[2*NH + idx] = (f16)a1;  comp[3*NH + idx] = (f16)a2;
    comp[4*NH + idx] = (f16)s00; comp[5*NH + idx] = (f16)s11; comp[6*NH + idx] = (f16)s22;
    comp[7*NH + idx] = (f16)s01; comp[8*NH + idx] = (f16)s02; comp[9*NH + idx] = (f16)s12;
}

// ---------------------------------------------------------------------------
// K2: channel-mix GEMM via fp16 MFMA.
// writeNode: f16 node-interleaved [node][10][128]; writePlane: f16 plane-major.
// ---------------------------------------------------------------------------
__global__ __launch_bounds__(256) void mix_mfma(const f16* __restrict__ A,
                                                const f16* __restrict__ WtT,
                                                f16* __restrict__ Cn,
                                                f16* __restrict__ Cp,
                                                int w0, int w1, int w2,
                                                int writeNode, int writePlane) {
    const int g = blockIdx.y;
    const int baseRow = (g == 0) ? 0   : (g == 1 ? NND   : 4*NND);
    const int Mg      = (g == 0) ? NND : (g == 1 ? 3*NND : 6*NND);
    const int row0 = blockIdx.x * 64;
    if (row0 >= Mg) return;
    const int wi = (g == 0) ? w0 : (g == 1 ? w1 : w2);
    const f16* B = WtT + (size_t)wi * 128 * 128;

    __shared__ f16 As[64 * 136];

    const int t = threadIdx.x;
    const int l = t & 63, wid = t >> 6, lr = l & 15, lh = l >> 4;

    #pragma unroll
    for (int i = 0; i < 4; i++) {
        int id = t + 256 * i;
        int r = id >> 4, ch = id & 15;
        int rr = row0 + r; if (rr >= Mg) rr = Mg - 1;
        *(half8*)&As[r*136 + ch*8] =
            *(const half8*)&A[((size_t)baseRow + rr) * HD + ch*8];
    }
    __syncthreads();

    floatx4 acc[8];
    #pragma unroll
    for (int n = 0; n < 8; n++) acc[n] = (floatx4)0.0f;

    #pragma unroll
    for (int k0 = 0; k0 < 128; k0 += 32) {
        half8 a = *(const half8*)&As[(wid*16 + lr)*136 + k0 + lh*8];
        #pragma unroll
        for (int n = 0; n < 8; n++) {
            half8 b = *(const half8*)&B[(size_t)(n*16 + lr)*128 + k0 + lh*8];
            acc[n] = __builtin_amdgcn_mfma_f32_16x16x32_f16(a, b, acc[n], 0, 0, 0);
        }
    }

    #pragma unroll
    for (int n = 0; n < 8; n++) {
        #pragma unroll
        for (int r = 0; r < 4; r++) {
            int gl = row0 + wid*16 + lh*4 + r;
            if (gl < Mg) {
                size_t grow = (size_t)baseRow + gl;
                int col = n*16 + lr;
                float val = acc[n][r];
                if (writePlane) Cp[grow * HD + col] = (f16)val;
                if (writeNode) {
                    int plane = (int)(grow / NND);
                    int node  = (int)(grow - (size_t)plane * NND);
                    Cn[((size_t)node * 10 + plane) * HD + col] = (f16)val;
                }
            }
        }
    }
}

// ---------------------------------------------------------------------------
// K3a: fused layers 1+2 (proven config: bounds(256,4), 33 KB pool).
// ---------------------------------------------------------------------------
__global__ __launch_bounds__(256, 4) void edge_gemm12(
    const float* __restrict__ edge_attr, const float* __restrict__ charges,
    const int* __restrict__ offs,
    const int* __restrict__ perm, const int* __restrict__ ssrc, const int* __restrict__ sdst,
    const f16* __restrict__ W1t, const float* __restrict__ b1,
    const f16* __restrict__ W2t, const float* __restrict__ b2,
    f16* __restrict__ x2b, int n0, int n1)
{
    __shared__ __align__(16) char pool[33280];
    f16* x0s  = (f16*)pool;                // 64*72*2  = 9216
    f16* x1s  = (f16*)(pool + 9216);       // 64*140*2 = 17920 (ends 27136)
    f16* x2st = (f16*)pool;                // 64*260*2 = 33280 (aliases, post-MFMA)
    __shared__ int srcS[64], dstS[64], permS[64];

    const int pbase = offs[n0];
    const int pend  = (n1 >= NND) ? NE : offs[n1];
    const int eb    = blockIdx.x * 64;
    if (pbase + eb >= pend) return;

    const int t = threadIdx.x;
    const int l = t & 63, wid = t >> 6, lr = l & 15, lh = l >> 4;

    if (t < 64) {
        int pe = pbase + eb + t;
        if (pe > NE - 1) pe = NE - 1;
        permS[t] = perm[pe];
        srcS[t]  = ssrc[pe];
        dstS[t]  = sdst[pe];
    }
    __syncthreads();

    // gather-stage: [attr(32) | charges[src](16) | charges[dst](16)]
    {
        int e = t >> 2, q = t & 3;
        #pragma unroll
        for (int jj = 0; jj < 2; jj++) {
            int j = q + jj*4;
            float4 va = *(const float4*)&edge_attr[(size_t)permS[e]*32 + j*4];
            half4 hv; hv[0]=(f16)va.x; hv[1]=(f16)va.y; hv[2]=(f16)va.z; hv[3]=(f16)va.w;
            *(half4*)&x0s[e*72 + j*4] = hv;
        }
        int node = (q < 2) ? srcS[e] : dstS[e];
        int qq   = (q < 2) ? q : (q - 2);
        int cb   = (q < 2) ? 32 : 48;
        #pragma unroll
        for (int jj = 0; jj < 2; jj++) {
            int j = qq + jj*2;
            float4 vc = *(const float4*)&charges[(size_t)node*16 + j*4];
            half4 hv; hv[0]=(f16)vc.x; hv[1]=(f16)vc.y; hv[2]=(f16)vc.z; hv[3]=(f16)vc.w;
            *(half4*)&x0s[e*72 + cb + j*4] = hv;
        }
    }
    __syncthreads();

    // ---- layer 1: [64 e][64 k] @ W1t[128][64] -> x1s (LDS) ----
    {
        floatx4 acc[2][4];
        #pragma unroll
        for (int n = 0; n < 2; n++)
            #pragma unroll
            for (int m = 0; m < 4; m++) acc[n][m] = (floatx4)0.0f;

        #pragma unroll
        for (int k0 = 0; k0 < 64; k0 += 32) {
            half8 a[4];
            #pragma unroll
            for (int m = 0; m < 4; m++)
                a[m] = *(const half8*)&x0s[(m*16 + lr)*72 + k0 + lh*8];
            #pragma unroll
            for (int n = 0; n < 2; n++) {
                half8 b = *(const half8*)&W1t[(size_t)(wid*32 + n*16 + lr)*64 + k0 + lh*8];
                #pragma unroll
                for (int m = 0; m < 4; m++)
                    acc[n][m] = __builtin_amdgcn_mfma_f32_16x16x32_f16(a[m], b, acc[n][m], 0, 0, 0);
            }
        }
        #pragma unroll
        for (int n = 0; n < 2; n++) {
            int col = wid*32 + n*16 + lr;
            float bb = b1[col];
            #pragma unroll
            for (int m = 0; m < 4; m++)
                #pragma unroll
                for (int r = 0; r < 4; r++)
                    x1s[(m*16 + lh*4 + r)*140 + col] = (f16)silu_f(acc[n][m][r] + bb);
        }
    }
    __syncthreads();

    // ---- layer 2: x1s[64][128] @ W2t[256][128] -> x2st (LDS) -> global ----
    {
        floatx4 acc[4][4];
        #pragma unroll
        for (int n = 0; n < 4; n++)
            #pragma unroll
            for (int m = 0; m < 4; m++) acc[n][m] = (floatx4)0.0f;

        #pragma unroll
        for (int k0 = 0; k0 < 128; k0 += 32) {
            half8 a[4];
            #pragma unroll
            for (int m = 0; m < 4; m++)
                a[m] = *(const half8*)&x1s[(m*16 + lr)*140 + k0 + lh*8];
            #pragma unroll
            for (int n = 0; n < 4; n++) {
                half8 b = *(const half8*)&W2t[(size_t)(wid*64 + n*16 + lr)*128 + k0 + lh*8];
                #pragma unroll
                for (int m = 0; m < 4; m++)
                    acc[n][m] = __builtin_amdgcn_mfma_f32_16x16x32_f16(a[m], b, acc[n][m], 0, 0, 0);
            }
        }
        __syncthreads();            // all x0s/x1s reads done before aliasing x2st
        #pragma unroll
        for (int n = 0; n < 4; n++) {
            int col = wid*64 + n*16 + lr;
            float bb = b2[col];
            #pragma unroll
            for (int m = 0; m < 4; m++)
                #pragma unroll
                for (int r = 0; r < 4; r++)
                    x2st[(m*16 + lh*4 + r)*260 + col] = (f16)silu_f(acc[n][m][r] + bb);
        }
    }
    __syncthreads();

    #pragma unroll
    for (int i = 0; i < 8; i++) {
        int c = t + 256 * i;
        int e = c >> 5, j = c & 31;
        *(half8*)&x2b[(size_t)(eb + e)*256 + j*8] = *(const half8*)&x2st[e*260 + j*8];
    }
}

// ---------------------------------------------------------------------------
// K3a': layer 3, N-SPLIT: blockIdx.y in {0,1} owns cols [ny*192, ny*192+192).
// acc[3][4] = 48 AGPR + ~55 VGPR fits bounds(256,4) cap of 128 (no spill).
// ---------------------------------------------------------------------------
__global__ __launch_bounds__(256, 4) void edge_gemm3(
    const float* __restrict__ edge_weight,
    const int* __restrict__ offs, const int* __restrict__ perm,
    const f16* __restrict__ x2b,
    const f16* __restrict__ W3t, const float* __restrict__ b3,
    f16* __restrict__ vbuf, int n0, int n1)
{
    __shared__ __align__(16) char pool[25088];
    f16* As    = (f16*)pool;               // 64*136*2 = 17408
    f16* stage = (f16*)pool;               // 64*196*2 = 25088 (aliases, post-MFMA)
    __shared__ float Cs[64];

    const int pbase = offs[n0];
    const int pend  = (n1 >= NND) ? NE : offs[n1];
    const int eb    = blockIdx.x * 64;
    const int ny    = blockIdx.y;          // column half: [ny*192, ny*192+192)
    if (pbase + eb >= pend) return;

    const int t = threadIdx.x;
    const int l = t & 63, wid = t >> 6, lr = l & 15, lh = l >> 4;

    if (t < 64) {
        int pe = pbase + eb + t;
        if (pe > NE - 1) pe = NE - 1;
        float w = edge_weight[perm[pe]];
        float c = 0.5f * (cosf(w * (float)(M_PI / 4.5)) + 1.0f);
        Cs[t] = (w < 4.5f) ? c : 0.0f;
    }

    floatx4 acc[3][4];
    #pragma unroll
    for (int n = 0; n < 3; n++)
        #pragma unroll
        for (int m = 0; m < 4; m++) acc[n][m] = (floatx4)0.0f;

    #pragma unroll
    for (int kb = 0; kb < 2; kb++) {
        __syncthreads();
        #pragma unroll
        for (int i = 0; i < 4; i++) {
            int id = t + 256 * i;
            int r = id >> 4, c = id & 15;
            *(half8*)&As[r*136 + c*8] =
                *(const half8*)&x2b[(size_t)(eb + r)*256 + kb*128 + c*8];
        }
        __syncthreads();

        #pragma unroll
        for (int k0 = 0; k0 < 128; k0 += 32) {
            half8 a[4];
            #pragma unroll
            for (int m = 0; m < 4; m++)
                a[m] = *(const half8*)&As[(m*16 + lr)*136 + k0 + lh*8];
            #pragma unroll
            for (int n = 0; n < 3; n++) {
                int col = ny*192 + wid*48 + n*16 + lr;
                half8 b = *(const half8*)&W3t[(size_t)col*256 + kb*128 + k0 + lh*8];
                #pragma unroll
                for (int m = 0; m < 4; m++)
                    acc[n][m] = __builtin_amdgcn_mfma_f32_16x16x32_f16(a[m], b, acc[n][m], 0, 0, 0);
            }
        }
    }
    __syncthreads();                 // As reads done before stage overwrite

    #pragma unroll
    for (int n = 0; n < 3; n++) {
        int lcol = wid*48 + n*16 + lr;
        int col  = ny*192 + lcol;
        float bb = b3[col];
        #pragma unroll
        for (int m = 0; m < 4; m++)
            #pragma unroll
            for (int r = 0; r < 4; r++) {
                int e = m*16 + lh*4 + r;
                stage[e*196 + lcol] = (f16)(silu_f(acc[n][m][r] + bb) * Cs[e]);
            }
    }
    __syncthreads();

    #pragma unroll
    for (int i = 0; i < 6; i++) {
        int c = t + 256 * i;              // 0..1535
        int e = c / 24, j = c - e * 24;   // 64 rows x 24 half8s
        *(half8*)&vbuf[(size_t)(eb + e)*384 + ny*192 + j*8] =
            *(const half8*)&stage[e*196 + j*8];
    }
}

// ---------------------------------------------------------------------------
// K3b: per-src-node gather-reduce + FUSED combine. Block = 1 node, 128 thr.
// ---------------------------------------------------------------------------
__global__ __launch_bounds__(128) void scatter_combine(
    const int* __restrict__ offs, const int* __restrict__ ends,
    const int* __restrict__ sdst, const f16* __restrict__ vbuf,
    const f16* __restrict__ Ych,
    f16* __restrict__ pre, int n0, int VC)
{
    const int s = n0 + blockIdx.x;
    const int h = threadIdx.x;
    const int pbase = offs[n0];
    const int p0 = offs[s], p1 = ends[s];

    float ps[10];
    #pragma unroll
    for (int c = 0; c < 10; c++) ps[c] = 0.f;

    int p = p0;
    for (; p + 1 < p1; p += 2) {
        int sl0 = p - pbase, sl1 = sl0 + 1;
        int d0 = sdst[p], d1 = sdst[p + 1];
        const f16* y0 = Ych + (size_t)d0 * 1280 + h;
        const f16* y1 = Ych + (size_t)d1 * 1280 + h;
        float va0 = (float)vbuf[(size_t)sl0*384 + h];
        float vb0 = (float)vbuf[(size_t)sl0*384 + 128 + h];
        float vc0 = (float)vbuf[(size_t)sl0*384 + 256 + h];
        float va1 = (float)vbuf[(size_t)sl1*384 + h];
        float vb1 = (float)vbuf[(size_t)sl1*384 + 128 + h];
        float vc1 = (float)vbuf[(size_t)sl1*384 + 256 + h];
        float y0r[10], y1r[10];
        #pragma unroll
        for (int c = 0; c < 10; c++) { y0r[c] = (float)y0[c*HD]; y1r[c] = (float)y1[c*HD]; }
        ps[0] = fmaf(va0, y0r[0], ps[0]);
        #pragma unroll
        for (int c = 1; c < 4; c++)  ps[c] = fmaf(vb0, y0r[c], ps[c]);
        #pragma unroll
        for (int c = 4; c < 10; c++) ps[c] = fmaf(vc0, y0r[c], ps[c]);
        ps[0] = fmaf(va1, y1r[0], ps[0]);
        #pragma unroll
        for (int c = 1; c < 4; c++)  ps[c] = fmaf(vb1, y1r[c], ps[c]);
        #pragma unroll
        for (int c = 4; c < 10; c++) ps[c] = fmaf(vc1, y1r[c], ps[c]);
    }
    if (p < p1) {
        int sl0 = p - pbase;
        int d0 = sdst[p];
        const f16* y0 = Ych + (size_t)d0 * 1280 + h;
        float va0 = (float)vbuf[(size_t)sl0*384 + h];
        float vb0 = (float)vbuf[(size_t)sl0*384 + 128 + h];
        float vc0 = (float)vbuf[(size_t)sl0*384 + 256 + h];
        float y0r[10];
        #pragma unroll
        for (int c = 0; c < 10; c++) y0r[c] = (float)y0[c*HD];
        ps[0] = fmaf(va0, y0r[0], ps[0]);
        #pragma unroll
        for (int c = 1; c < 4; c++)  ps[c] = fmaf(vb0, y0r[c], ps[c]);
        #pragma unroll
        for (int c = 4; c < 10; c++) ps[c] = fmaf(vc0, y0r[c], ps[c]);
    }

    // ---- fused combine: T = M@Y + Y@M, decompose, normalize ----
    const f16* ys = Ych + (size_t)s * 1280 + h;
    float yI  = (float)ys[0*HD];
    float ya0 = (float)ys[1*HD], ya1 = (float)ys[2*HD], ya2 = (float)ys[3*HD];
    float ys00 = (float)ys[4*HD], ys11 = (float)ys[5*HD], ys22 = (float)ys[6*HD];
    float ys01 = (float)ys[7*HD], ys02 = (float)ys[8*HD], ys12 = (float)ys[9*HD];

    float M[3][3] = {
        { ps[0] + ps[4],  ps[7] - ps[3],  ps[8] + ps[2] },
        { ps[7] + ps[3],  ps[0] + ps[5],  ps[9] - ps[1] },
        { ps[8] - ps[2],  ps[9] + ps[1],  ps[0] + ps[6] } };
    float Y[3][3] = {
        { yI + ys00,  ys01 - ya2, ys02 + ya1 },
        { ys01 + ya2, yI + ys11,  ys12 - ya0 },
        { ys02 - ya1, ys12 + ya0, yI + ys22  } };

    float T[3][3];
    #pragma unroll
    for (int r = 0; r < 3; r++)
        #pragma unroll
        for (int c = 0; c < 3; c++) {
            float acc = 0.f;
            #pragma unroll
            for (int k = 0; k < 3; k++)
                acc += M[r][k] * Y[k][c] + Y[r][k] * M[k][c];
            T[r][c] = acc;
        }

    float tr3 = (T[0][0] + T[1][1] + T[2][2]) * (1.0f / 3.0f);
    float nsq = 0.f;
    #pragma unroll
    for (int r = 0; r < 3; r++)
        #pragma unroll
        for (int c = 0; c < 3; c++) nsq = fmaf(T[r][c], T[r][c], nsq);
    float inv = 1.0f / (nsq + 1.0f);

    const size_t idx = (size_t)s * HD + h;
    pre[0*(size_t)NH + idx] = (f16)(tr3 * inv);
    pre[1*(size_t)NH + idx] = (f16)(0.5f * (T[2][1] - T[1][2]) * inv);
    pre[2*(size_t)NH + idx] = (f16)(0.5f * (T[0][2] - T[2][0]) * inv);
    pre[3*(size_t)NH + idx] = (f16)(0.5f * (T[1][0] - T[0][1]) * inv);
    pre[4*(size_t)NH + idx] = (f16)((T[0][0] - tr3) * inv);
    pre[5*(size_t)NH + idx] = (f16)((T[1][1] - tr3) * inv);
    pre[6*(size_t)NH + idx] = (f16)((T[2][2] - tr3) * inv);
    pre[7*(size_t)NH + idx] = (f16)(0.5f * (T[0][1] + T[1][0]) * inv);
    pre[8*(size_t)NH + idx] = (f16)(0.5f * (T[0][2] + T[2][0]) * inv);
    pre[9*(size_t)NH + idx] = (f16)(0.5f * (T[1][2] + T[2][1]) * inv);
}

// ---------------------------------------------------------------------------
// K6: dX from postmix fields (f16 plane-major); out = Xn + dX + dX@dX
// ---------------------------------------------------------------------------
__global__ __launch_bounds__(256) void final_out(const f16* __restrict__ post,
                                                 const float* __restrict__ X,
                                                 float* __restrict__ out) {
    int idx = blockIdx.x * 256 + threadIdx.x;
    if (idx >= NH) return;

    float dI  = (float)post[0*(size_t)NH + idx];
    float da0 = (float)post[1*(size_t)NH + idx], da1 = (float)post[2*(size_t)NH + idx], da2 = (float)post[3*(size_t)NH + idx];
    float ds00 = (float)post[4*(size_t)NH + idx], ds11 = (float)post[5*(size_t)NH + idx], ds22 = (float)post[6*(size_t)NH + idx];
    float ds01 = (float)post[7*(size_t)NH + idx], ds02 = (float)post[8*(size_t)NH + idx], ds12 = (float)post[9*(size_t)NH + idx];

    float D[3][3] = {
        { dI + ds00,  ds01 - da2, ds02 + da1 },
        { ds01 + da2, dI + ds11,  ds12 - da0 },
        { ds02 - da1, ds12 + da0, dI + ds22  } };

    const float* xp = X + (size_t)idx * 9;
    float x[9];
    #pragma unroll
    for (int i = 0; i < 9; i++) x[i] = xp[i];
    float nsq = 0.f;
    #pragma unroll
    for (int i = 0; i < 9; i++) nsq = fmaf(x[i], x[i], nsq);
    float inv = 1.0f / (nsq + 1.0f);

    float* op = out + (size_t)idx * 9;
    #pragma unroll
    for (int r = 0; r < 3; r++)
        #pragma unroll
        for (int c = 0; c < 3; c++) {
            float p = 0.f;
            #pragma unroll
            for (int k = 0; k < 3; k++) p = fmaf(D[r][k], D[k][c], p);
            op[r*3 + c] = x[r*3 + c] * inv + D[r][c] + p;
        }
}

// ---------------------------------------------------------------------------
extern "C" void kernel_launch(void* const* d_in, const int* in_sizes, int n_in,
                              void* d_out, int out_size, void* d_ws, size_t ws_size,
                              hipStream_t stream) {
    const float* X       = (const float*)d_in[0];
    const float* charges = (const float*)d_in[1];
    const float* ew      = (const float*)d_in[2];
    const float* ea      = (const float*)d_in[3];
    const float* W1      = (const float*)d_in[4];
    const float* b1      = (const float*)d_in[5];
    const float* W2      = (const float*)d_in[6];
    const float* b2      = (const float*)d_in[7];
    const float* W3      = (const float*)d_in[8];
    const float* b3      = (const float*)d_in[9];
    const float* Wt      = (const float*)d_in[10];
    const int*   eidx    = (const int*)d_in[11];
    float* out = (float*)d_out;

    f16*   posth = (f16*)d_ws;                      // post (mix2 out, f16): 25.6 MB
    f16*   fh16  = posth + (size_t)10 * NH;         // comp (f16), then preh: 25.6 MB
    f16*   ych   = fh16 + (size_t)10 * NH;          // [NND][10][128] f16: 25.6 MB
    f16*   w1t   = ych + (size_t)10 * NH;
    f16*   w2t   = w1t + 128*64;
    f16*   w3t   = w2t + 256*128;
    f16*   wtT   = w3t + 384*256;                   // [6][128][128] f16
    int*   hist   = (int*)(wtT + 6*128*128);
    int*   offs   = hist + NND;
    int*   cursor = offs + NND;                     // run-end after scatter
    int*   perm   = cursor + NND;
    int*   ssrc   = perm + NE;
    int*   sdst   = ssrc + NE;
    f16*   vbuf   = (f16*)(sdst + NE);              // [VC][3][128] f16, chunked

    // choose chunk count: need VC*(384+256)*2 bytes after 'vbuf'
    size_t used = (size_t)((char*)vbuf - (char*)d_ws);
    int Q, VC;
    if      (used + (size_t)160000 * 1280 <= ws_size) { Q = 1; VC = 160000; }
    else if (used + (size_t) 84480 * 1280 <= ws_size) { Q = 2; VC = 84480;  }
    else if (used + (size_t) 48000 * 1280 <= ws_size) { Q = 4; VC = 48000;  }
    else                                              { Q = 8; VC = 24320;  }
    f16* x2b = vbuf + (size_t)VC * 384;             // [VC][256]

    hipMemsetAsync(hist, 0, NND * sizeof(int), stream);

    w_prep<<<928, 256, 0, stream>>>(W1, W2, W3, Wt, w1t, w2t, w3t, wtT);
    node_prep<<<NH / 256, 256, 0, stream>>>(X, fh16);

    hist_kernel<<<(NE + 255) / 256, 256, 0, stream>>>(eidx, hist);
    scan_kernel<<<1, 1024, 0, stream>>>(hist, offs, cursor);
    scatter_kernel<<<(NE + 255) / 256, 256, 0, stream>>>(eidx, cursor, perm, ssrc, sdst);

    dim3 gmix((6 * NND + 63) / 64, 3);
    // mix #1: comp -> Ych (f16 node-interleaved) only
    mix_mfma<<<gmix, 256, 0, stream>>>(fh16, wtT, ych, posth, 0, 1, 2, 1, 0);

    const int nodesPer = NND / Q;
    for (int q = 0; q < Q; q++) {
        int n0 = q * nodesPer, n1 = n0 + nodesPer;
        int nb = VC / 64;
        edge_gemm12<<<nb, 256, 0, stream>>>(ea, charges, offs, perm, ssrc, sdst,
                                            w1t, b1, w2t, b2, x2b, n0, n1);
        edge_gemm3<<<dim3(nb, 2), 256, 0, stream>>>(ew, offs, perm, x2b, w3t, b3,
                                                    vbuf, n0, n1);
        scatter_combine<<<nodesPer, 128, 0, stream>>>(offs, cursor, sdst, vbuf,
                                                      ych, fh16, n0, VC);
    }

    // mix #2: preh -> posth (f16 plane-major)
    mix_mfma<<<gmix, 256, 0, stream>>>(fh16, wtT, ych, posth, 3, 4, 5, 0, 1);

    final_out<<<NH / 256, 256, 0, stream>>>(posth, X, out);
}